// Round 1
// baseline (105.893 us; speedup 1.0000x reference)
//
#include <hip/hip_runtime.h>
#include <math.h>

// Problem constants (from reference)
#define B_DIM 16
#define T_DIM 2048
#define D_DIM 4096
#define G_DIM 8
#define GS    512
#define H_DIM 16
#define CHUNKS 16          // t-chunks per (b,g)
#define NPARTIAL (B_DIM * G_DIM * CHUNKS)   // 2048

// Output layout (float32, concatenated flat in return order)
#define OUT_DBITS   0        // [16,8]   = 128
#define OUT_GIDX    128      // [16,4096]= 65536
#define OUT_EMB     65664    // [16,8,512] = 65536
#define OUT_BLOSS   131200   // scalar
#define OUT_DIV     131201   // scalar
#define OUT_BPROBS  131202   // [16,8] = 128

// ---------------------------------------------------------------------------
// Kernel 1: reduce importance_scores [B,T,D] -> 2048 double partials.
// block = (b, g, chunk); each block sums T_chunk(=128) x GS(=512) floats.
// ---------------------------------------------------------------------------
__global__ __launch_bounds__(256) void k_reduce(const float* __restrict__ scores,
                                                double* __restrict__ partials) {
    const int bid   = blockIdx.x;        // [0,2048)
    const int pair  = bid >> 4;          // b*8+g
    const int chunk = bid & 15;
    const int b = pair >> 3;
    const int g = pair & 7;
    const int tid = threadIdx.x;

    // float4 base for this (b,g): offsets are multiples of 4 floats
    const float4* base = reinterpret_cast<const float4*>(
        scores + (size_t)b * T_DIM * D_DIM + (size_t)g * GS);
    const int t0 = chunk * 128;

    double acc = 0.0;
    #pragma unroll 4
    for (int it = 0; it < 64; ++it) {
        const int l = tid + it * 256;        // [0,16384)
        const int t = l >> 7;                // 128 float4 per t-row slice
        const int q = l & 127;
        float4 v = base[(size_t)(t0 + t) * (D_DIM / 4) + q];
        acc += (double)v.x + (double)v.y + (double)v.z + (double)v.w;
    }

    __shared__ double sd[256];
    sd[tid] = acc;
    __syncthreads();
    #pragma unroll
    for (int s = 128; s > 0; s >>= 1) {
        if (tid < s) sd[tid] += sd[tid + s];
        __syncthreads();
    }
    if (tid == 0) partials[bid] = sd[0];
}

// ---------------------------------------------------------------------------
// Kernel 2: finish group means, run the tiny MLP + gumbel softmax + alloc +
// discretize; write discrete_bits, bit_probs, scalars; stash bit_w in ws.
// ---------------------------------------------------------------------------
__global__ __launch_bounds__(128) void k_mlp(const double* __restrict__ partials,
                                             const float* __restrict__ u,
                                             const float* __restrict__ W1,
                                             const float* __restrict__ b1,
                                             const float* __restrict__ ln_g,
                                             const float* __restrict__ ln_b,
                                             const float* __restrict__ W2,
                                             const float* __restrict__ b2,
                                             float* __restrict__ out,
                                             float* __restrict__ bitw) {
    __shared__ float gi[B_DIM * G_DIM];   // group_imp [16][8]
    __shared__ float ent[B_DIM];
    __shared__ float bitsum[B_DIM];
    const int tid = threadIdx.x;

    if (tid < 128) {
        double s = 0.0;
        #pragma unroll
        for (int c = 0; c < CHUNKS; ++c) s += partials[tid * CHUNKS + c];
        gi[tid] = (float)(s * (1.0 / ((double)T_DIM * (double)GS)));
    }
    __syncthreads();

    if (tid < B_DIM) {
        const int b = tid;
        // h = GELU(group_imp @ W1 + b1)   (exact gelu: 0.5x(1+erf(x/sqrt2)))
        float h[H_DIM];
        #pragma unroll
        for (int i = 0; i < H_DIM; ++i) {
            float a = b1[i];
            #pragma unroll
            for (int g = 0; g < G_DIM; ++g) a += gi[b * G_DIM + g] * W1[g * H_DIM + i];
            h[i] = 0.5f * a * (1.0f + erff(a * 0.70710678118654752440f));
        }
        // LayerNorm over H
        float mu = 0.f;
        #pragma unroll
        for (int i = 0; i < H_DIM; ++i) mu += h[i];
        mu *= (1.0f / (float)H_DIM);
        float var = 0.f;
        #pragma unroll
        for (int i = 0; i < H_DIM; ++i) { float d = h[i] - mu; var += d * d; }
        var *= (1.0f / (float)H_DIM);
        const float inv = rsqrtf(var + 1e-5f);
        #pragma unroll
        for (int i = 0; i < H_DIM; ++i) h[i] = (h[i] - mu) * inv * ln_g[i] + ln_b[i];

        // logits + gumbel
        float z[G_DIM];
        #pragma unroll
        for (int j = 0; j < G_DIM; ++j) {
            float a = b2[j];
            #pragma unroll
            for (int i = 0; i < H_DIM; ++i) a += h[i] * W2[i * G_DIM + j];
            const float uu = u[b * G_DIM + j];
            const float gum = -logf(-logf(uu + 1e-8f) + 1e-8f);
            z[j] = a + gum;
        }
        // softmax over 8
        float m = z[0];
        #pragma unroll
        for (int j = 1; j < G_DIM; ++j) m = fmaxf(m, z[j]);
        float p[G_DIM]; float ssum = 0.f;
        #pragma unroll
        for (int j = 0; j < G_DIM; ++j) { p[j] = expf(z[j] - m); ssum += p[j]; }
        const float rs = 1.0f / ssum;

        // alloc, budget rescale, clip
        float alloc[G_DIM]; float asum = 0.f;
        #pragma unroll
        for (int j = 0; j < G_DIM; ++j) {
            p[j] *= rs;
            alloc[j] = 2.0f + p[j] * 6.0f;
            asum += alloc[j];
        }
        const float scale = 32.0f / asum;   // budget = 4 * 8

        float entb = 0.f, bs = 0.f;
        #pragma unroll
        for (int j = 0; j < G_DIM; ++j) {
            float a = alloc[j] * scale;
            a = fminf(fmaxf(a, 2.0f), 8.0f);
            // nearest of {2,4,8}; argmin tie-break -> lower index
            const float hard = (a <= 3.0f) ? 2.0f : ((a <= 6.0f) ? 4.0f : 8.0f);
            out[OUT_DBITS + b * G_DIM + j]  = hard;
            out[OUT_BPROBS + b * G_DIM + j] = p[j];
            entb += p[j] * logf(p[j] + 1e-8f);
            bs += hard;
            // bit_w = softmax(exp(-|hard - levels|)) over 3 levels
            const float x0 = expf(-fabsf(hard - 2.0f));
            const float x1 = expf(-fabsf(hard - 4.0f));
            const float x2 = expf(-fabsf(hard - 8.0f));
            const float mm = fmaxf(x0, fmaxf(x1, x2));
            const float e0 = expf(x0 - mm), e1 = expf(x1 - mm), e2 = expf(x2 - mm);
            const float ir = 1.0f / (e0 + e1 + e2);
            bitw[(b * G_DIM + j) * 3 + 0] = e0 * ir;
            bitw[(b * G_DIM + j) * 3 + 1] = e1 * ir;
            bitw[(b * G_DIM + j) * 3 + 2] = e2 * ir;
        }
        ent[b] = entb;
        bitsum[b] = bs;
    }
    __syncthreads();

    if (tid == 0) {
        float tb = 0.f, te = 0.f;
        #pragma unroll
        for (int b = 0; b < B_DIM; ++b) { tb += bitsum[b]; te += ent[b]; }
        const float mb = tb * (1.0f / (float)(B_DIM * G_DIM));
        out[OUT_BLOSS] = (mb - 4.0f) * (mb - 4.0f);
        out[OUT_DIV]   = -te * (1.0f / (float)B_DIM);
    }
}

// ---------------------------------------------------------------------------
// Kernel 3: embeddings = bit_w @ bit_embeddings, plus constant group_indices.
// One float4 of each per thread; 64 blocks x 256 threads = 16384 float4.
// ---------------------------------------------------------------------------
__global__ __launch_bounds__(256) void k_emb(const float* __restrict__ bitw,
                                             const float* __restrict__ emb,
                                             float* __restrict__ out) {
    const int l = blockIdx.x * 256 + threadIdx.x;   // [0,16384)
    const int b   = l >> 10;        // 4096/4 float4 per batch row
    const int rem = l & 1023;
    const int g   = rem >> 7;       // 512/4 float4 per group
    const int j4  = rem & 127;

    const float4* e4 = reinterpret_cast<const float4*>(emb);  // [3][128]
    const float4 e0 = e4[0 * 128 + j4];
    const float4 e1 = e4[1 * 128 + j4];
    const float4 e2 = e4[2 * 128 + j4];
    const float w0 = bitw[(b * G_DIM + g) * 3 + 0];
    const float w1 = bitw[(b * G_DIM + g) * 3 + 1];
    const float w2 = bitw[(b * G_DIM + g) * 3 + 2];

    float4 r;
    r.x = w0 * e0.x + w1 * e1.x + w2 * e2.x;
    r.y = w0 * e0.y + w1 * e1.y + w2 * e2.y;
    r.z = w0 * e0.z + w1 * e1.z + w2 * e2.z;
    r.w = w0 * e0.w + w1 * e1.w + w2 * e2.w;

    float4* o4 = reinterpret_cast<float4*>(out);
    o4[(OUT_EMB / 4) + l] = r;

    const float gv = (float)g;                   // d // 512, same for all 4 lanes of the float4
    o4[(OUT_GIDX / 4) + l] = make_float4(gv, gv, gv, gv);
}

// ---------------------------------------------------------------------------
extern "C" void kernel_launch(void* const* d_in, const int* in_sizes, int n_in,
                              void* d_out, int out_size, void* d_ws, size_t ws_size,
                              hipStream_t stream) {
    const float* scores = (const float*)d_in[0];
    const float* u      = (const float*)d_in[1];
    const float* W1     = (const float*)d_in[2];
    const float* b1     = (const float*)d_in[3];
    const float* ln_g   = (const float*)d_in[4];
    const float* ln_b   = (const float*)d_in[5];
    const float* W2     = (const float*)d_in[6];
    const float* b2     = (const float*)d_in[7];
    const float* emb    = (const float*)d_in[8];
    float* out = (float*)d_out;

    double* partials = (double*)d_ws;                                   // 2048 * 8 B
    float*  bitw     = (float*)((char*)d_ws + NPARTIAL * sizeof(double)); // 384 * 4 B

    k_reduce<<<NPARTIAL, 256, 0, stream>>>(scores, partials);
    k_mlp<<<1, 128, 0, stream>>>(partials, u, W1, b1, ln_g, ln_b, W2, b2, out, bitw);
    k_emb<<<64, 256, 0, stream>>>(bitw, emb, out);
}